// Round 10
// baseline (294.164 us; speedup 1.0000x reference)
//
#include <hip/hip_runtime.h>

// ---------------------------------------------------------------------------
// CoupledFEMSolver — fused gather assembly v5.
//   * index_build (one kernel): per-partition LDS hist -> block scan ->
//     transposed prefix P2[node][partition] -> partition-contiguous 4B packed
//     entries {e*4+a}.
//   * fused_gather, 1024-thread blocks (2 blocks/CU @ 78.7KB LDS = FULL
//     occupancy): coalesced P2 prologue; Qb wave-scan; O(1) visit->partition
//     table (pvt, reuses claim buf); ONE visit per thread (rows ~781 < 1024;
//     streaming tail for the impossible >1024 case); single-claim arbitrated
//     plain-write LDS accumulation; plane-major accumulators -> contiguous
//     b128 stores; diagonal block in registers; M_s written inline.
//
// Geometry per tet (double math; K entries ~ 1/det reach ~1e14):
//   det = r1.(r2 x r3); g1=(r2xr3)/det, g2=(r3xr1)/det, g3=(r1xr2)/det,
//   g0=-(g1+g2+g3); vol=|det|/6
// Fluid:  K_e[a][b] = vol*(ga.gb); M_e[a][b] = vol*(a==b ? .3 : .1)
// Solid:  K block (a,b) entry (i,j) =
//   vol*(lam*ga_i*gb_j + mu*ga_j*gb_i + (i==j)*mu*(ga.gb));
//   M_s diagonal only: rho*vol/4 per dof.
// ---------------------------------------------------------------------------

#define G_PART 256
#define GT 1024           // gather block threads
#define GW (GT / 64)      // waves per gather block

__device__ __forceinline__ float sel4(float x0, float x1, float x2, float x3, int a) {
    float r = x0;
    r = (a == 1) ? x1 : r;
    r = (a == 2) ? x2 : r;
    r = (a == 3) ? x3 : r;
    return r;
}
__device__ __forceinline__ int sel4i(int x0, int x1, int x2, int x3, int a) {
    int r = x0;
    r = (a == 1) ? x1 : r;
    r = (a == 2) ? x2 : r;
    r = (a == 3) ? x3 : r;
    return r;
}

__device__ __forceinline__ float wave_reduce(float v) {
#pragma unroll
    for (int m = 1; m < 64; m <<= 1) v += __shfl_xor(v, m, 64);
    return v;
}

// double-precision tet geometry -> f32 gradients g1..g3 and volume
__device__ __forceinline__ void tet_geom_f(const float* __restrict__ nodes,
                                           int n0, int n1, int n2, int n3_,
                                           float& gx1, float& gy1, float& gz1,
                                           float& gx2, float& gy2, float& gz2,
                                           float& gx3, float& gy3, float& gz3,
                                           float& volf)
{
    const float* q0 = nodes + 3ll * n0;
    const float* q1 = nodes + 3ll * n1;
    const float* q2 = nodes + 3ll * n2;
    const float* q3 = nodes + 3ll * n3_;
    double p0x = q0[0], p0y = q0[1], p0z = q0[2];
    double r1x = (double)q1[0] - p0x, r1y = (double)q1[1] - p0y, r1z = (double)q1[2] - p0z;
    double r2x = (double)q2[0] - p0x, r2y = (double)q2[1] - p0y, r2z = (double)q2[2] - p0z;
    double r3x = (double)q3[0] - p0x, r3y = (double)q3[1] - p0y, r3z = (double)q3[2] - p0z;
    double c23x = r2y*r3z - r2z*r3y, c23y = r2z*r3x - r2x*r3z, c23z = r2x*r3y - r2y*r3x;
    double det = r1x*c23x + r1y*c23y + r1z*c23z;
    double inv = 1.0 / det;
    double c31x = r3y*r1z - r3z*r1y, c31y = r3z*r1x - r3x*r1z, c31z = r3x*r1y - r3y*r1x;
    double c12x = r1y*r2z - r1z*r2y, c12y = r1z*r2x - r1x*r2z, c12z = r1x*r2y - r1y*r2x;
    gx1 = (float)(c23x*inv); gy1 = (float)(c23y*inv); gz1 = (float)(c23z*inv);
    gx2 = (float)(c31x*inv); gy2 = (float)(c31y*inv); gz2 = (float)(c31z*inv);
    gx3 = (float)(c12x*inv); gy3 = (float)(c12y*inv); gz3 = (float)(c12z*inv);
    volf = (float)(fabs(det) / 6.0);
}

// tail-only: 8-step bisection over Qb prefix (rows with >1024 visits; ~never)
__device__ __forceinline__ int fetch_entry_bs(const int* __restrict__ ent,
                                              const int* __restrict__ Sb,
                                              const int* __restrict__ Qb,
                                              int chunk4, int v)
{
    int lo = 0, hi = 255;
#pragma unroll
    for (int it = 0; it < 8; ++it) {
        int mid = (lo + hi + 1) >> 1;
        bool ge = (Qb[mid] <= v);
        lo = ge ? mid : lo;
        hi = ge ? hi : mid - 1;
    }
    return ent[(size_t)lo * chunk4 + Sb[lo] + (v - Qb[lo])];
}

// single named-register visit state
#define DECL_VISIT() \
    float gxx0=0,gxx1=0,gxx2=0,gxx3=0, gyy0=0,gyy1=0,gyy2=0,gyy3=0, \
          gzz0=0,gzz1=0,gzz2=0,gzz3=0, volv=0, ga0=0,ga1=0,ga2=0; \
    int va=0, vc0=0,vc1=0,vc2=0,vc3=0;

#define LOAD_VISIT(packed_) do { \
    int e_ = (packed_) >> 2; va = (packed_) & 3; \
    int4 nd_ = elems4[e_]; \
    vc0 = nd_.x; vc1 = nd_.y; vc2 = nd_.z; vc3 = nd_.w; \
    tet_geom_f(nodes, vc0, vc1, vc2, vc3, \
        gxx1,gyy1,gzz1, gxx2,gyy2,gzz2, gxx3,gyy3,gzz3, volv); \
    gxx0 = -(gxx1+gxx2+gxx3); \
    gyy0 = -(gyy1+gyy2+gyy3); \
    gzz0 = -(gzz1+gzz2+gzz3); \
    ga0 = sel4(gxx0,gxx1,gxx2,gxx3,va); \
    ga1 = sel4(gyy0,gyy1,gyy2,gyy3,va); \
    ga2 = sel4(gzz0,gzz1,gzz2,gzz3,va); \
} while (0)

#define DIAG_S() do { \
    float lv_ = lam*volv, mv_ = mu*volv, lm_ = lv_+mv_; \
    float mgg_ = mv_*(ga0*ga0 + ga1*ga1 + ga2*ga2); \
    d00 += lm_*ga0*ga0 + mgg_; d01 += lm_*ga0*ga1;        d02 += lm_*ga0*ga2; \
    d10 += lm_*ga1*ga0;        d11 += lm_*ga1*ga1 + mgg_; d12 += lm_*ga1*ga2; \
    d20 += lm_*ga2*ga0;        d21 += lm_*ga2*ga1;        d22 += lm_*ga2*ga2 + mgg_; \
    vsum += volv; } while (0)

#define DIAG_F() do { \
    dK += volv*(ga0*ga0 + ga1*ga1 + ga2*ga2); \
    dM += volv*0.3f; } while (0)

#define PAIR_S(b_) do { \
    float gb0_ = sel4(gxx0,gxx1,gxx2,gxx3,b_); \
    float gb1_ = sel4(gyy0,gyy1,gyy2,gyy3,b_); \
    float gb2_ = sel4(gzz0,gzz1,gzz2,gzz3,b_); \
    col = sel4i(vc0,vc1,vc2,vc3,b_); \
    float lv_ = lam*volv, mv_ = mu*volv; \
    float la0_ = lv_*ga0, la1_ = lv_*ga1, la2_ = lv_*ga2; \
    float ma0_ = mv_*ga0, ma1_ = mv_*ga1, ma2_ = mv_*ga2; \
    float mgg_ = mv_*(ga0*gb0_ + ga1*gb1_ + ga2*gb2_); \
    v00 = la0_*gb0_ + ma0_*gb0_ + mgg_; v01 = la0_*gb1_ + ma1_*gb0_; v02 = la0_*gb2_ + ma2_*gb0_; \
    v10 = la1_*gb0_ + ma0_*gb1_; v11 = la1_*gb1_ + ma1_*gb1_ + mgg_; v12 = la1_*gb2_ + ma2_*gb1_; \
    v20 = la2_*gb0_ + ma0_*gb2_; v21 = la2_*gb1_ + ma1_*gb2_; v22 = la2_*gb2_ + ma2_*gb2_ + mgg_; \
} while (0)

#define PAIR_F(b_) do { \
    float gb0_ = sel4(gxx0,gxx1,gxx2,gxx3,b_); \
    float gb1_ = sel4(gyy0,gyy1,gyy2,gyy3,b_); \
    float gb2_ = sel4(gzz0,gzz1,gzz2,gzz3,b_); \
    col = sel4i(vc0,vc1,vc2,vc3,b_); \
    vK = volv*(ga0*gb0_ + ga1*gb1_ + ga2*gb2_); \
    vM = volv*0.1f; \
} while (0)

// ------------------- one-kernel partition-local index build ------------------
__global__ void __launch_bounds__(256)
index_build(const int4* __restrict__ fe, const int4* __restrict__ se,
            int* __restrict__ entF, int* __restrict__ entS,
            int* __restrict__ PF, int* __restrict__ PS,
            int nf, int ns, int n, int chunkF, int chunkS)
{
    extern __shared__ int h[];            // n + 256
    int* wsum = h + n;
    const bool solid = blockIdx.x >= G_PART;
    const int b = solid ? blockIdx.x - G_PART : blockIdx.x;
    const int4* elems = solid ? se : fe;
    const int nelem = solid ? ns : nf;
    const int chunk = solid ? chunkS : chunkF;
    int* P2 = solid ? PS : PF;            // layout: P2[node][partition]
    int* entries = (solid ? entS : entF) + (size_t)b * 4 * chunk;

    const int t = threadIdx.x;
    const int beg = b * chunk, end = min(nelem, beg + chunk);

    for (int i = t; i < n; i += 256) h[i] = 0;
    __syncthreads();
    for (int e = beg + t; e < end; e += 256) {
        int4 nd = elems[e];
        atomicAdd(&h[nd.x], 1);
        atomicAdd(&h[nd.y], 1);
        atomicAdd(&h[nd.z], 1);
        atomicAdd(&h[nd.w], 1);
    }
    __syncthreads();

    // block exclusive scan of h[0..n)
    const int cs = (n + 255) / 256;
    const int base = t * cs;
    int s = 0;
    for (int k = 0; k < cs; ++k) {
        int i = base + k;
        if (i < n) s += h[i];
    }
    wsum[t] = s;
    __syncthreads();
    for (int d = 1; d < 256; d <<= 1) {
        int v = (t >= d) ? wsum[t - d] : 0;
        __syncthreads();
        wsum[t] += v;
        __syncthreads();
    }
    int run = (t == 0) ? 0 : wsum[t - 1];
    for (int k = 0; k < cs; ++k) {
        int i = base + k;
        if (i < n) {
            int c = h[i]; h[i] = run;
            P2[(size_t)i * G_PART + b] = run;
            run += c;
        }
    }
    if (t == 255) P2[(size_t)n * G_PART + b] = wsum[255];
    __syncthreads();

    // place packed entries (h[] now holds cursors = prefix)
    for (int e = beg + t; e < end; e += 256) {
        int4 nd = elems[e];
        int p;
        p = atomicAdd(&h[nd.x], 1); entries[p] = e * 4 + 0;
        p = atomicAdd(&h[nd.y], 1); entries[p] = e * 4 + 1;
        p = atomicAdd(&h[nd.z], 1); entries[p] = e * 4 + 2;
        p = atomicAdd(&h[nd.w], 1); entries[p] = e * 4 + 3;
    }
}

// ------------------------------ fused gather --------------------------------
// blocks [0,n): solid rows; [n,2n): fluid rows.  1024 threads/block.
__global__ void __launch_bounds__(GT, 2)
fused_gather(const int* __restrict__ entF, const int* __restrict__ PF,
             const int* __restrict__ entS, const int* __restrict__ PS,
             const int4* __restrict__ fe, const int4* __restrict__ se,
             const float* __restrict__ nodes,
             float* __restrict__ Kf, float* __restrict__ Mf,
             float* __restrict__ Ks, float* __restrict__ Ms,
             const float* __restrict__ E_p, const float* __restrict__ nu_p,
             const float* __restrict__ rho_p, int n, int n3,
             int chunk4F, int chunk4S)
{
    extern __shared__ unsigned char smem[];
    const int tid = threadIdx.x;
    const int bid = blockIdx.x;

    if (bid < n) {
        // ================= solid =================
        const int r = bid;
        const int4* elems4 = se;
        float* val = (float*)smem;                               // 9n (3 planes of n3)
        unsigned short* claim = (unsigned short*)(val + 9 * n);  // n (pvt in prologue)
        int* Sb = (int*)(claim + n);                             // 256
        int* Qb = Sb + 256;                                      // 257
        float* dred = (float*)(Qb + 257);                        // GW*10 + 10

        {
            float4* v = (float4*)val;
            int cnt = (9 * n) >> 2;
            for (int k = tid; k < cnt; k += GT) v[k] = make_float4(0.f,0.f,0.f,0.f);
        }
        if (tid < 256) {
            int s0 = PS[(size_t)r * G_PART + tid];
            int e0 = PS[(size_t)(r + 1) * G_PART + tid];
            Sb[tid] = s0;
            Qb[tid] = e0 - s0;     // counts; scanned below
        }
        __syncthreads();
        if (tid < 64) {
            int c0 = Qb[4*tid], c1 = Qb[4*tid+1], c2 = Qb[4*tid+2], c3 = Qb[4*tid+3];
            int s = c0 + c1 + c2 + c3;
            int x = s;
#pragma unroll
            for (int d = 1; d < 64; d <<= 1) {
                int y = __shfl_up(x, d, 64);
                if (tid >= d) x += y;
            }
            int ex = x - s;
            Qb[4*tid] = ex; Qb[4*tid+1] = ex + c0;
            Qb[4*tid+2] = ex + c0 + c1; Qb[4*tid+3] = ex + c0 + c1 + c2;
            if (tid == 63) Qb[256] = ex + s;
        }
        __syncthreads();
        const int T = Qb[256];
        const int pvLim = min(T, n);

        // O(1) visit->partition table in claim buffer (consumed before loop)
        if (tid < 256) {
            int v0 = Qb[tid], v1 = min(Qb[tid + 1], pvLim);
            for (int v = v0; v < v1; ++v) claim[v] = (unsigned short)tid;
        }
        __syncthreads();

        float E = *E_p, nu = *nu_p, rho = *rho_p;
        float coeff = E / ((1.f + nu) * (1.f - 2.f * nu));
        float lam = coeff * nu;
        float mu  = coeff * (1.f - 2.f * nu) * 0.5f;

        float d00=0,d01=0,d02=0,d10=0,d11=0,d12=0,d20=0,d21=0,d22=0,vsum=0;
        DECL_VISIT();

        bool pending = false;
        int s = 3, col = 0, nextV = tid + GT;
        float v00=0,v01=0,v02=0,v10=0,v11=0,v12=0,v20=0,v21=0,v22=0;

        if (tid < T) {
            int part = (tid < pvLim) ? (int)claim[tid]
                                     : 0;   // unreachable: pvLim==T when T<=n
            int pk = (tid < pvLim)
                   ? entS[(size_t)part * chunk4S + Sb[part] + (tid - Qb[part])]
                   : fetch_entry_bs(entS, Sb, Qb, chunk4S, tid);
            LOAD_VISIT(pk); DIAG_S(); s = 0;
        }

        auto advanceS = [&]() {
            while (!pending) {
                if (s >= 3) {
                    if (nextV >= T) return;
                    int pk = fetch_entry_bs(entS, Sb, Qb, chunk4S, nextV);  // ~never
                    LOAD_VISIT(pk); DIAG_S();
                    s = 0; nextV += GT;
                }
                int b_ = s + ((s >= va) ? 1 : 0);
                PAIR_S(b_);
                ++s; pending = true;
            }
        };

        advanceS();
        __syncthreads();   // pvt consumption done; claim array reusable

        int live = __syncthreads_count(pending ? 1 : 0);
        while (live) {
            if (pending) claim[col] = (unsigned short)tid;
            __syncthreads();
            if (pending && claim[col] == (unsigned short)tid) {
                float* p0 = val + 3 * col;
                float* p1 = p0 + n3;
                float* p2 = p1 + n3;
                p0[0]+=v00; p0[1]+=v01; p0[2]+=v02;
                p1[0]+=v10; p1[1]+=v11; p1[2]+=v12;
                p2[0]+=v20; p2[1]+=v21; p2[2]+=v22;
                pending = false;
                advanceS();
            }
            live = __syncthreads_count(pending ? 1 : 0);
        }

        // diagonal reduction
        d00=wave_reduce(d00); d01=wave_reduce(d01); d02=wave_reduce(d02);
        d10=wave_reduce(d10); d11=wave_reduce(d11); d12=wave_reduce(d12);
        d20=wave_reduce(d20); d21=wave_reduce(d21); d22=wave_reduce(d22);
        vsum=wave_reduce(vsum);
        if ((tid & 63) == 0) {
            int w = tid >> 6;
            dred[w*10+0]=d00; dred[w*10+1]=d01; dred[w*10+2]=d02;
            dred[w*10+3]=d10; dred[w*10+4]=d11; dred[w*10+5]=d12;
            dred[w*10+6]=d20; dred[w*10+7]=d21; dred[w*10+8]=d22;
            dred[w*10+9]=vsum;
        }
        __syncthreads();
        if (tid < 10) {
            float t_ = 0.f;
            for (int w = 0; w < GW; ++w) t_ += dred[w*10 + tid];
            dred[GW*10 + tid] = t_;
        }
        __syncthreads();
        if (tid < 9) {
            int i = tid / 3, j = tid - 3 * i;
            val[i * n3 + 3 * r + j] += dred[GW*10 + tid];
        }
        __syncthreads();

        // Ks rows 3r..3r+2: plane-major -> pure b128 copies
        int q = n3 >> 2;
        for (int k4 = tid; k4 < 3 * q; k4 += GT) {
            int i = (k4 >= q) + (k4 >= 2*q);
            int t4 = k4 - i * q;
            float4 w = ((const float4*)(val + i * n3))[t4];
            ((float4*)(Ks + (size_t)(3*r + i) * n3))[t4] = w;
        }
        // Ms rows: zeros + diagonal
        float diag = rho * 0.25f * dred[GW*10 + 9];
        for (int k4 = tid; k4 < 3 * q; k4 += GT) {
            int i = (k4 >= q) + (k4 >= 2*q);
            int t4 = k4 - i * q;
            int dcol = 3*r + i;
            int base = t4 << 2;
            float4 w;
            w.x = (base + 0 == dcol) ? diag : 0.f;
            w.y = (base + 1 == dcol) ? diag : 0.f;
            w.z = (base + 2 == dcol) ? diag : 0.f;
            w.w = (base + 3 == dcol) ? diag : 0.f;
            ((float4*)(Ms + (size_t)(3*r + i) * n3))[t4] = w;
        }
    } else {
        // ================= fluid =================
        const int r = bid - n;
        const int4* elems4 = fe;
        float* val = (float*)smem;                               // 2n (K plane, M plane)
        unsigned short* claim = (unsigned short*)(val + 2 * n);  // n
        int* Sb = (int*)(claim + n);                             // 256
        int* Qb = Sb + 256;                                      // 257
        float* dred = (float*)(Qb + 257);                        // GW*2 + 2

        {
            float4* v = (float4*)val;
            int cnt = (2 * n) >> 2;
            for (int k = tid; k < cnt; k += GT) v[k] = make_float4(0.f,0.f,0.f,0.f);
        }
        if (tid < 256) {
            int s0 = PF[(size_t)r * G_PART + tid];
            int e0 = PF[(size_t)(r + 1) * G_PART + tid];
            Sb[tid] = s0;
            Qb[tid] = e0 - s0;
        }
        __syncthreads();
        if (tid < 64) {
            int c0 = Qb[4*tid], c1 = Qb[4*tid+1], c2 = Qb[4*tid+2], c3 = Qb[4*tid+3];
            int s = c0 + c1 + c2 + c3;
            int x = s;
#pragma unroll
            for (int d = 1; d < 64; d <<= 1) {
                int y = __shfl_up(x, d, 64);
                if (tid >= d) x += y;
            }
            int ex = x - s;
            Qb[4*tid] = ex; Qb[4*tid+1] = ex + c0;
            Qb[4*tid+2] = ex + c0 + c1; Qb[4*tid+3] = ex + c0 + c1 + c2;
            if (tid == 63) Qb[256] = ex + s;
        }
        __syncthreads();
        const int T = Qb[256];
        const int pvLim = min(T, n);

        if (tid < 256) {
            int v0 = Qb[tid], v1 = min(Qb[tid + 1], pvLim);
            for (int v = v0; v < v1; ++v) claim[v] = (unsigned short)tid;
        }
        __syncthreads();

        float dK = 0.f, dM = 0.f;
        DECL_VISIT();

        bool pending = false;
        int s = 3, col = 0, nextV = tid + GT;
        float vK = 0.f, vM = 0.f;

        if (tid < T) {
            int part = (tid < pvLim) ? (int)claim[tid] : 0;
            int pk = (tid < pvLim)
                   ? entF[(size_t)part * chunk4F + Sb[part] + (tid - Qb[part])]
                   : fetch_entry_bs(entF, Sb, Qb, chunk4F, tid);
            LOAD_VISIT(pk); DIAG_F(); s = 0;
        }

        auto advanceF = [&]() {
            while (!pending) {
                if (s >= 3) {
                    if (nextV >= T) return;
                    int pk = fetch_entry_bs(entF, Sb, Qb, chunk4F, nextV);
                    LOAD_VISIT(pk); DIAG_F();
                    s = 0; nextV += GT;
                }
                int b_ = s + ((s >= va) ? 1 : 0);
                PAIR_F(b_);
                ++s; pending = true;
            }
        };

        advanceF();
        __syncthreads();

        int live = __syncthreads_count(pending ? 1 : 0);
        while (live) {
            if (pending) claim[col] = (unsigned short)tid;
            __syncthreads();
            if (pending && claim[col] == (unsigned short)tid) {
                val[col]     += vK;
                val[n + col] += vM;
                pending = false;
                advanceF();
            }
            live = __syncthreads_count(pending ? 1 : 0);
        }

        dK = wave_reduce(dK);
        dM = wave_reduce(dM);
        if ((tid & 63) == 0) { int w = tid >> 6; dred[w*2+0] = dK; dred[w*2+1] = dM; }
        __syncthreads();
        if (tid < 2) {
            float t_ = 0.f;
            for (int w = 0; w < GW; ++w) t_ += dred[w*2 + tid];
            dred[GW*2 + tid] = t_;
        }
        __syncthreads();
        if (tid == 0) { val[r] += dred[GW*2]; val[n + r] += dred[GW*2 + 1]; }
        __syncthreads();

        size_t rowoff = (size_t)r * n;
        int qf = n >> 2;
        float4* K4 = (float4*)(Kf + rowoff);
        float4* M4 = (float4*)(Mf + rowoff);
        for (int c4 = tid; c4 < qf; c4 += GT) {
            K4[c4] = ((const float4*)val)[c4];
            M4[c4] = ((const float4*)(val + n))[c4];
        }
    }
}

// --------------------------- fallback scatter path ---------------------------
__device__ __forceinline__ void tet_grads_d(const float* __restrict__ nodes,
                                            const int* ni, double g[4][3], double& vol)
{
    double p[4][3];
#pragma unroll
    for (int a = 0; a < 4; ++a) {
        const float* q = nodes + 3ll * ni[a];
        p[a][0] = (double)q[0]; p[a][1] = (double)q[1]; p[a][2] = (double)q[2];
    }
    double r1[3], r2[3], r3[3];
#pragma unroll
    for (int k = 0; k < 3; ++k) {
        r1[k] = p[1][k] - p[0][k];
        r2[k] = p[2][k] - p[0][k];
        r3[k] = p[3][k] - p[0][k];
    }
    double c23[3] = { r2[1]*r3[2]-r2[2]*r3[1], r2[2]*r3[0]-r2[0]*r3[2], r2[0]*r3[1]-r2[1]*r3[0] };
    double det = r1[0]*c23[0] + r1[1]*c23[1] + r1[2]*c23[2];
    double inv = 1.0 / det;
    double c31[3] = { r3[1]*r1[2]-r3[2]*r1[1], r3[2]*r1[0]-r3[0]*r1[2], r3[0]*r1[1]-r3[1]*r1[0] };
    double c12[3] = { r1[1]*r2[2]-r1[2]*r2[1], r1[2]*r2[0]-r1[0]*r2[2], r1[0]*r2[1]-r1[1]*r2[0] };
#pragma unroll
    for (int k = 0; k < 3; ++k) {
        g[1][k] = c23[k]*inv; g[2][k] = c31[k]*inv; g[3][k] = c12[k]*inv;
        g[0][k] = -(g[1][k] + g[2][k] + g[3][k]);
    }
    vol = fabs(det) / 6.0;
}

__global__ void __launch_bounds__(256)
fluid_assemble(const float* __restrict__ nodes, const int* __restrict__ elems,
               float* __restrict__ Kf, float* __restrict__ Mf, int nelem, int n)
{
    int e = blockIdx.x * blockDim.x + threadIdx.x;
    if (e >= nelem) return;
    const int4 nd = *reinterpret_cast<const int4*>(elems + 4ll * e);
    int ni[4] = { nd.x, nd.y, nd.z, nd.w };
    double g[4][3], vol;
    tet_grads_d(nodes, ni, g, vol);
#pragma unroll
    for (int a = 0; a < 4; ++a) {
        long long rowoff = (long long)ni[a] * n;
#pragma unroll
        for (int b = 0; b < 4; ++b) {
            double kv = vol * (g[a][0]*g[b][0] + g[a][1]*g[b][1] + g[a][2]*g[b][2]);
            double mv = vol * (a == b ? 0.3 : 0.1);
            atomicAdd(Kf + rowoff + ni[b], (float)kv);
            atomicAdd(Mf + rowoff + ni[b], (float)mv);
        }
    }
}

__global__ void __launch_bounds__(256)
solid_assemble(const float* __restrict__ nodes, const int* __restrict__ elems,
               float* __restrict__ Ks, float* __restrict__ Ms,
               const float* __restrict__ E_p, const float* __restrict__ nu_p,
               const float* __restrict__ rho_p, int nelem, int n3)
{
    int e = blockIdx.x * blockDim.x + threadIdx.x;
    if (e >= nelem) return;
    double E = (double)*E_p, nu = (double)*nu_p, rho = (double)*rho_p;
    double coeff = E / ((1.0 + nu) * (1.0 - 2.0 * nu));
    double lam = coeff * nu, mu = coeff * (1.0 - 2.0 * nu) * 0.5;
    const int4 nd = *reinterpret_cast<const int4*>(elems + 4ll * e);
    int ni[4] = { nd.x, nd.y, nd.z, nd.w };
    double g[4][3], vol;
    tet_grads_d(nodes, ni, g, vol);
    double lv = lam * vol, mv = mu * vol;
#pragma unroll
    for (int a = 0; a < 4; ++a) {
        long long row0 = 3ll * ni[a];
#pragma unroll
        for (int b = 0; b < 4; ++b) {
            long long col0 = 3ll * ni[b];
            double gg = g[a][0]*g[b][0] + g[a][1]*g[b][1] + g[a][2]*g[b][2];
#pragma unroll
            for (int i = 0; i < 3; ++i) {
                float* rowp = Ks + (row0 + i) * (long long)n3 + col0;
#pragma unroll
                for (int j = 0; j < 3; ++j) {
                    double val = lv * g[a][i] * g[b][j] + mv * g[a][j] * g[b][i];
                    if (i == j) val += mv * gg;
                    atomicAdd(rowp + j, (float)val);
                }
            }
        }
        float mval = (float)(rho * vol * 0.25);
#pragma unroll
        for (int i = 0; i < 3; ++i) {
            long long d = row0 + i;
            atomicAdd(Ms + d * (long long)n3 + d, mval);
        }
    }
}

// ---------------------------------------------------------------------------
extern "C" void kernel_launch(void* const* d_in, const int* in_sizes, int n_in,
                              void* d_out, int out_size, void* d_ws, size_t ws_size,
                              hipStream_t stream)
{
    const float* nodes = (const float*)d_in[0];
    const int*   fe    = (const int*)d_in[1];
    const int*   se    = (const int*)d_in[2];
    const float* E_p   = (const float*)d_in[3];
    const float* nu_p  = (const float*)d_in[4];
    const float* rho_p = (const float*)d_in[5];

    const int n  = in_sizes[0] / 3;
    const int nf = in_sizes[1] / 4;
    const int ns = in_sizes[2] / 4;
    const int n3 = 3 * n;

    float* out = (float*)d_out;
    float* Kf = out;
    float* Mf = Kf + (size_t)n * n;
    float* Ks = Mf + (size_t)n * n;
    float* Ms = Ks + (size_t)n3 * n3;

    const int chunkF = (nf + G_PART - 1) / G_PART;
    const int chunkS = (ns + G_PART - 1) / G_PART;

    size_t pos = 0;
    auto take = [&](size_t bytes) {
        size_t p = pos;
        pos = (pos + bytes + 255) & ~(size_t)255;
        return p;
    };
    size_t entF_o = take((size_t)4 * chunkF * G_PART * 4);
    size_t entS_o = take((size_t)4 * chunkS * G_PART * 4);
    size_t PF_o   = take((size_t)(n + 1) * G_PART * 4);
    size_t PS_o   = take((size_t)(n + 1) * G_PART * 4);

    size_t gatherLds = (size_t)9 * n * 4 + (size_t)n * 2 + (256 + 257) * 4
                     + (GW * 10 + 10) * 4;
    size_t indexLds  = (size_t)(n + 256) * 4;
    bool gather_ok = (pos <= ws_size) && ((n & 3) == 0) && (n <= 65535) &&
                     (gatherLds <= 80 * 1024) && (indexLds <= 64 * 1024);

    const int bs = 256;

    if (!gather_ok) {
        hipMemsetAsync(d_out, 0, (size_t)out_size * sizeof(float), stream);
        fluid_assemble<<<(nf + bs - 1) / bs, bs, 0, stream>>>(nodes, fe, Kf, Mf, nf, n);
        solid_assemble<<<(ns + bs - 1) / bs, bs, 0, stream>>>(nodes, se, Ks, Ms,
                                                              E_p, nu_p, rho_p, ns, n3);
        return;
    }

    char* ws = (char*)d_ws;
    int* entF = (int*)(ws + entF_o);
    int* entS = (int*)(ws + entS_o);
    int* PF   = (int*)(ws + PF_o);
    int* PS   = (int*)(ws + PS_o);

    const int4* fe4 = (const int4*)fe;
    const int4* se4 = (const int4*)se;

    index_build<<<2 * G_PART, bs, indexLds, stream>>>(fe4, se4, entF, entS, PF, PS,
                                                      nf, ns, n, chunkF, chunkS);
    fused_gather<<<2 * n, GT, gatherLds, stream>>>(entF, PF, entS, PS,
                                                   fe4, se4, nodes,
                                                   Kf, Mf, Ks, Ms,
                                                   E_p, nu_p, rho_p, n, n3,
                                                   4 * chunkF, 4 * chunkS);
}

// Round 11
// 184.482 us; speedup vs baseline: 1.5945x; 1.5945x over previous
//
#include <hip/hip_runtime.h>

// ---------------------------------------------------------------------------
// CoupledFEMSolver — fused gather assembly v6: counting-sort-by-column,
// exclusive-owner accumulation (NO claim loop, NO LDS-atomic accumulation).
//
// index_build (proven ~16us): per-partition LDS hist -> block scan ->
//   transposed prefix P2[node][partition] -> partition-contiguous 4B entries.
// fused_gather (512 thr, 2 blocks/CU):
//   prologue: coalesced P2 rows -> Sb/Qb; wave-scan -> per-partition prefix.
//   stage:    each visit fetched once (bsearch over Qb), geometry in doubles,
//             10 floats + packed cols staged in LDS (stride 13 = odd ->
//             conflict-free random reads); diag accumulated in stage-thread
//             registers; column histogram built in the same pass.
//   sort:     exclusive scan of column counts -> cursor scatter of pair ids
//             (v<<4|a<<2|b). start(c) = pcnt[c-1] post-scatter (prefix trick).
//   own:      thread tid owns cols {tid + k*512}; sums its pairs' 9 values
//             (solid) / 2 values (fluid) in REGISTERS — single writer, no
//             arbitration.
//   store:    owners write directly to global: consecutive lanes own
//             consecutive cols -> contiguous coalesced stores; M_s rows
//             (zeros + diag) written the same way; no val[] staging at all.
//
// Geometry per tet (double math; K entries ~ 1/det reach ~1e14):
//   det = r1.(r2 x r3); g1=(r2xr3)/det, g2=(r3xr1)/det, g3=(r1xr2)/det,
//   g0=-(g1+g2+g3); vol=|det|/6
// Fluid:  K_e[a][b] = vol*(ga.gb); M_e[a][b] = vol*(a==b ? .3 : .1)
// Solid:  K block (a,b) entry (i,j) =
//   vol*(lam*ga_i*gb_j + mu*ga_j*gb_i + (i==j)*mu*(ga.gb));
//   M_s diagonal only: rho*vol/4 per dof.
// ---------------------------------------------------------------------------

#define G_PART 256
#define BT 512            // gather block threads
#define GW (BT / 64)      // waves per gather block
#define TCAP 1024         // staged visits per batch (rows ~781 +- 28; 8.7 sigma)
#define NCPT 4            // owned cols per thread (needs n <= NCPT*BT)
#define VSTRIDE 13        // floats per staged visit (odd -> bank spread)

__device__ __forceinline__ float sel4(float x0, float x1, float x2, float x3, int a) {
    float r = x0;
    r = (a == 1) ? x1 : r;
    r = (a == 2) ? x2 : r;
    r = (a == 3) ? x3 : r;
    return r;
}
__device__ __forceinline__ int sel4i(int x0, int x1, int x2, int x3, int a) {
    int r = x0;
    r = (a == 1) ? x1 : r;
    r = (a == 2) ? x2 : r;
    r = (a == 3) ? x3 : r;
    return r;
}

__device__ __forceinline__ float wave_reduce(float v) {
#pragma unroll
    for (int m = 1; m < 64; m <<= 1) v += __shfl_xor(v, m, 64);
    return v;
}

// double-precision tet geometry -> f32 gradients g1..g3 and volume
__device__ __forceinline__ void tet_geom_f(const float* __restrict__ nodes,
                                           int n0, int n1, int n2, int n3_,
                                           float& gx1, float& gy1, float& gz1,
                                           float& gx2, float& gy2, float& gz2,
                                           float& gx3, float& gy3, float& gz3,
                                           float& volf)
{
    const float* q0 = nodes + 3ll * n0;
    const float* q1 = nodes + 3ll * n1;
    const float* q2 = nodes + 3ll * n2;
    const float* q3 = nodes + 3ll * n3_;
    double p0x = q0[0], p0y = q0[1], p0z = q0[2];
    double r1x = (double)q1[0] - p0x, r1y = (double)q1[1] - p0y, r1z = (double)q1[2] - p0z;
    double r2x = (double)q2[0] - p0x, r2y = (double)q2[1] - p0y, r2z = (double)q2[2] - p0z;
    double r3x = (double)q3[0] - p0x, r3y = (double)q3[1] - p0y, r3z = (double)q3[2] - p0z;
    double c23x = r2y*r3z - r2z*r3y, c23y = r2z*r3x - r2x*r3z, c23z = r2x*r3y - r2y*r3x;
    double det = r1x*c23x + r1y*c23y + r1z*c23z;
    double inv = 1.0 / det;
    double c31x = r3y*r1z - r3z*r1y, c31y = r3z*r1x - r3x*r1z, c31z = r3x*r1y - r3y*r1x;
    double c12x = r1y*r2z - r1z*r2y, c12y = r1z*r2x - r1x*r2z, c12z = r1x*r2y - r1y*r2x;
    gx1 = (float)(c23x*inv); gy1 = (float)(c23y*inv); gz1 = (float)(c23z*inv);
    gx2 = (float)(c31x*inv); gy2 = (float)(c31y*inv); gz2 = (float)(c31z*inv);
    gx3 = (float)(c12x*inv); gy3 = (float)(c12y*inv); gz3 = (float)(c12z*inv);
    volf = (float)(fabs(det) / 6.0);
}

// 8-step bisection over Qb prefix -> entry for visit v
__device__ __forceinline__ int fetch_entry_bs(const int* __restrict__ ent,
                                              const int* __restrict__ Sb,
                                              const int* __restrict__ Qb,
                                              int chunk4, int v)
{
    int lo = 0, hi = 255;
#pragma unroll
    for (int it = 0; it < 8; ++it) {
        int mid = (lo + hi + 1) >> 1;
        bool ge = (Qb[mid] <= v);
        lo = ge ? mid : lo;
        hi = ge ? hi : mid - 1;
    }
    return ent[(size_t)lo * chunk4 + Sb[lo] + (v - Qb[lo])];
}

// ------------------- one-kernel partition-local index build ------------------
__global__ void __launch_bounds__(256)
index_build(const int4* __restrict__ fe, const int4* __restrict__ se,
            int* __restrict__ entF, int* __restrict__ entS,
            int* __restrict__ PF, int* __restrict__ PS,
            int nf, int ns, int n, int chunkF, int chunkS)
{
    extern __shared__ int h[];            // n + 256
    int* wsum = h + n;
    const bool solid = blockIdx.x >= G_PART;
    const int b = solid ? blockIdx.x - G_PART : blockIdx.x;
    const int4* elems = solid ? se : fe;
    const int nelem = solid ? ns : nf;
    const int chunk = solid ? chunkS : chunkF;
    int* P2 = solid ? PS : PF;            // layout: P2[node][partition]
    int* entries = (solid ? entS : entF) + (size_t)b * 4 * chunk;

    const int t = threadIdx.x;
    const int beg = b * chunk, end = min(nelem, beg + chunk);

    for (int i = t; i < n; i += 256) h[i] = 0;
    __syncthreads();
    for (int e = beg + t; e < end; e += 256) {
        int4 nd = elems[e];
        atomicAdd(&h[nd.x], 1);
        atomicAdd(&h[nd.y], 1);
        atomicAdd(&h[nd.z], 1);
        atomicAdd(&h[nd.w], 1);
    }
    __syncthreads();

    const int cs = (n + 255) / 256;
    const int base = t * cs;
    int s = 0;
    for (int k = 0; k < cs; ++k) {
        int i = base + k;
        if (i < n) s += h[i];
    }
    wsum[t] = s;
    __syncthreads();
    for (int d = 1; d < 256; d <<= 1) {
        int v = (t >= d) ? wsum[t - d] : 0;
        __syncthreads();
        wsum[t] += v;
        __syncthreads();
    }
    int run = (t == 0) ? 0 : wsum[t - 1];
    for (int k = 0; k < cs; ++k) {
        int i = base + k;
        if (i < n) {
            int c = h[i]; h[i] = run;
            P2[(size_t)i * G_PART + b] = run;
            run += c;
        }
    }
    if (t == 255) P2[(size_t)n * G_PART + b] = wsum[255];
    __syncthreads();

    for (int e = beg + t; e < end; e += 256) {
        int4 nd = elems[e];
        int p;
        p = atomicAdd(&h[nd.x], 1); entries[p] = e * 4 + 0;
        p = atomicAdd(&h[nd.y], 1); entries[p] = e * 4 + 1;
        p = atomicAdd(&h[nd.z], 1); entries[p] = e * 4 + 2;
        p = atomicAdd(&h[nd.w], 1); entries[p] = e * 4 + 3;
    }
}

// ------------------------------ fused gather --------------------------------
// blocks [0,n): solid rows; [n,2n): fluid rows.  512 threads/block.
__global__ void __launch_bounds__(BT, 2)
fused_gather(const int* __restrict__ entF, const int* __restrict__ PF,
             const int* __restrict__ entS, const int* __restrict__ PS,
             const int4* __restrict__ fe, const int4* __restrict__ se,
             const float* __restrict__ nodes,
             float* __restrict__ Kf, float* __restrict__ Mf,
             float* __restrict__ Ks, float* __restrict__ Ms,
             const float* __restrict__ E_p, const float* __restrict__ nu_p,
             const float* __restrict__ rho_p, int n, int n3,
             int chunk4F, int chunk4S)
{
    extern __shared__ unsigned char smem[];
    float* vis  = (float*)smem;                      // TCAP * VSTRIDE
    int*   pcnt = (int*)(vis + TCAP * VSTRIDE);      // n
    int*   plist = pcnt + n;                         // 3*TCAP
    int*   Sb   = plist + 3 * TCAP;                  // 256
    int*   Qb   = Sb + 256;                          // 257
    int*   wsp  = Qb + 257;                          // GW
    float* dred = (float*)(wsp + GW);                // GW*10 + 10

    const int tid = threadIdx.x;
    const int bid = blockIdx.x;
    const bool isSolid = bid < n;
    const int r = isSolid ? bid : bid - n;
    const int* ent = isSolid ? entS : entF;
    const int* P2  = isSolid ? PS : PF;
    const int4* elems4 = isSolid ? se : fe;
    const int chunk4 = isSolid ? chunk4S : chunk4F;

    // ---- prologue: partition ranges + prefix ----
    if (tid < 256) {
        int s0 = P2[(size_t)r * G_PART + tid];
        int e0 = P2[(size_t)(r + 1) * G_PART + tid];
        Sb[tid] = s0;
        Qb[tid] = e0 - s0;
    }
    __syncthreads();
    if (tid < 64) {
        int c0 = Qb[4*tid], c1 = Qb[4*tid+1], c2 = Qb[4*tid+2], c3 = Qb[4*tid+3];
        int s = c0 + c1 + c2 + c3;
        int x = s;
#pragma unroll
        for (int d = 1; d < 64; d <<= 1) {
            int y = __shfl_up(x, d, 64);
            if (tid >= d) x += y;
        }
        int ex = x - s;
        Qb[4*tid] = ex; Qb[4*tid+1] = ex + c0;
        Qb[4*tid+2] = ex + c0 + c1; Qb[4*tid+3] = ex + c0 + c1 + c2;
        if (tid == 63) Qb[256] = ex + s;
    }
    __syncthreads();
    const int T = Qb[256];

    const float E = *E_p, nu = *nu_p, rho = *rho_p;
    const float coeff = E / ((1.f + nu) * (1.f - 2.f * nu));
    const float lam = coeff * nu;
    const float mu  = coeff * (1.f - 2.f * nu) * 0.5f;

    if (isSolid) {
        // ========================= solid =========================
        float acc[NCPT][9];
#pragma unroll
        for (int k = 0; k < NCPT; ++k)
#pragma unroll
            for (int j = 0; j < 9; ++j) acc[k][j] = 0.f;
        float d00=0,d01=0,d02=0,d10=0,d11=0,d12=0,d20=0,d21=0,d22=0,vsum=0;

        for (int vb = 0; vb < T; vb += TCAP) {
            const int Tb = min(T - vb, TCAP);
            for (int c = tid; c < n; c += BT) pcnt[c] = 0;
            __syncthreads();

            // stage + diag + hist
            for (int v = tid; v < Tb; v += BT) {
                int pk = fetch_entry_bs(ent, Sb, Qb, chunk4, vb + v);
                int e_ = pk >> 2, a = pk & 3;
                int4 nd = elems4[e_];
                float g1x,g1y,g1z,g2x,g2y,g2z,g3x,g3y,g3z,vol;
                tet_geom_f(nodes, nd.x, nd.y, nd.z, nd.w,
                           g1x,g1y,g1z, g2x,g2y,g2z, g3x,g3y,g3z, vol);
                float g0x = -(g1x+g2x+g3x), g0y = -(g1y+g2y+g3y), g0z = -(g1z+g2z+g3z);
                float* V = vis + v * VSTRIDE;
                V[0]=g1x; V[1]=g1y; V[2]=g1z; V[3]=g2x; V[4]=g2y; V[5]=g2z;
                V[6]=g3x; V[7]=g3y; V[8]=g3z; V[9]=vol;
                ((int*)V)[10] = nd.x | (nd.y << 11) | (a << 22);
                ((int*)V)[11] = nd.z | (nd.w << 11);
                float ga0 = sel4(g0x,g1x,g2x,g3x,a);
                float ga1 = sel4(g0y,g1y,g2y,g3y,a);
                float ga2 = sel4(g0z,g1z,g2z,g3z,a);
                {
                    float lv = lam*vol, mv = mu*vol, lm = lv+mv;
                    float mgg = mv*(ga0*ga0 + ga1*ga1 + ga2*ga2);
                    d00 += lm*ga0*ga0 + mgg; d01 += lm*ga0*ga1;       d02 += lm*ga0*ga2;
                    d10 += lm*ga1*ga0;       d11 += lm*ga1*ga1 + mgg; d12 += lm*ga1*ga2;
                    d20 += lm*ga2*ga0;       d21 += lm*ga2*ga1;       d22 += lm*ga2*ga2 + mgg;
                    vsum += vol;
                }
#pragma unroll
                for (int s = 0; s < 3; ++s) {
                    int b = s + ((s >= a) ? 1 : 0);
                    int cb = sel4i(nd.x, nd.y, nd.z, nd.w, b);
                    atomicAdd(&pcnt[cb], 1);
                }
            }
            __syncthreads();

            // exclusive scan of pcnt[0..n)
            {
                const int cs = (n + BT - 1) / BT;
                int cb0 = tid * cs;
                int s = 0;
                for (int k = 0; k < cs; ++k) {
                    int i = cb0 + k;
                    if (i < n) s += pcnt[i];
                }
                int x = s;
#pragma unroll
                for (int d = 1; d < 64; d <<= 1) {
                    int y = __shfl_up(x, d, 64);
                    if ((tid & 63) >= d) x += y;
                }
                if ((tid & 63) == 63) wsp[tid >> 6] = x;
                __syncthreads();
                if (tid == 0) {
                    int run = 0;
                    for (int w = 0; w < GW; ++w) { int t_ = wsp[w]; wsp[w] = run; run += t_; }
                }
                __syncthreads();
                int ex = (x - s) + wsp[tid >> 6];
                for (int k = 0; k < cs; ++k) {
                    int i = cb0 + k;
                    if (i < n) { int c0 = pcnt[i]; pcnt[i] = ex; ex += c0; }
                }
            }
            __syncthreads();

            // scatter pair ids
            for (int v = tid; v < Tb; v += BT) {
                const float* V = vis + v * VSTRIDE;
                int w0 = ((const int*)V)[10], w1 = ((const int*)V)[11];
                int a = (w0 >> 22) & 3;
                int c0 = w0 & 2047, c1 = (w0 >> 11) & 2047;
                int c2 = w1 & 2047, c3 = (w1 >> 11) & 2047;
#pragma unroll
                for (int s = 0; s < 3; ++s) {
                    int b = s + ((s >= a) ? 1 : 0);
                    int cb = sel4i(c0, c1, c2, c3, b);
                    int p = atomicAdd(&pcnt[cb], 1);
                    plist[p] = (v << 4) | (a << 2) | b;
                }
            }
            __syncthreads();

            // exclusive-owner accumulate
#pragma unroll
            for (int k = 0; k < NCPT; ++k) {
                int c = tid + k * BT;
                if (c < n) {
                    int s0 = (c == 0) ? 0 : pcnt[c - 1];
                    int s1 = pcnt[c];
                    for (int p = s0; p < s1; ++p) {
                        int pe = plist[p];
                        int v = pe >> 4, a = (pe >> 2) & 3, b = pe & 3;
                        const float* V = vis + v * VSTRIDE;
                        float g1x=V[0],g1y=V[1],g1z=V[2],g2x=V[3],g2y=V[4],g2z=V[5],
                              g3x=V[6],g3y=V[7],g3z=V[8],vol=V[9];
                        float g0x=-(g1x+g2x+g3x), g0y=-(g1y+g2y+g3y), g0z=-(g1z+g2z+g3z);
                        float ga0=sel4(g0x,g1x,g2x,g3x,a);
                        float ga1=sel4(g0y,g1y,g2y,g3y,a);
                        float ga2=sel4(g0z,g1z,g2z,g3z,a);
                        float gb0=sel4(g0x,g1x,g2x,g3x,b);
                        float gb1=sel4(g0y,g1y,g2y,g3y,b);
                        float gb2=sel4(g0z,g1z,g2z,g3z,b);
                        float lv=lam*vol, mv=mu*vol;
                        float la0=lv*ga0, la1=lv*ga1, la2=lv*ga2;
                        float ma0=mv*ga0, ma1=mv*ga1, ma2=mv*ga2;
                        float mgg=mv*(ga0*gb0 + ga1*gb1 + ga2*gb2);
                        acc[k][0] += la0*gb0 + ma0*gb0 + mgg;
                        acc[k][1] += la0*gb1 + ma1*gb0;
                        acc[k][2] += la0*gb2 + ma2*gb0;
                        acc[k][3] += la1*gb0 + ma0*gb1;
                        acc[k][4] += la1*gb1 + ma1*gb1 + mgg;
                        acc[k][5] += la1*gb2 + ma2*gb1;
                        acc[k][6] += la2*gb0 + ma0*gb2;
                        acc[k][7] += la2*gb1 + ma1*gb2;
                        acc[k][8] += la2*gb2 + ma2*gb2 + mgg;
                    }
                }
            }
            __syncthreads();
        }

        // diag reduction
        d00=wave_reduce(d00); d01=wave_reduce(d01); d02=wave_reduce(d02);
        d10=wave_reduce(d10); d11=wave_reduce(d11); d12=wave_reduce(d12);
        d20=wave_reduce(d20); d21=wave_reduce(d21); d22=wave_reduce(d22);
        vsum=wave_reduce(vsum);
        if ((tid & 63) == 0) {
            int w = tid >> 6;
            dred[w*10+0]=d00; dred[w*10+1]=d01; dred[w*10+2]=d02;
            dred[w*10+3]=d10; dred[w*10+4]=d11; dred[w*10+5]=d12;
            dred[w*10+6]=d20; dred[w*10+7]=d21; dred[w*10+8]=d22;
            dred[w*10+9]=vsum;
        }
        __syncthreads();
        if (tid < 10) {
            float t_ = 0.f;
            for (int w = 0; w < GW; ++w) t_ += dred[w*10 + tid];
            dred[GW*10 + tid] = t_;
        }
        __syncthreads();

        // direct coalesced store: Ks rows 3r..3r+2 and Ms rows (zeros+diag)
        const float msdiag = rho * 0.25f * dred[GW*10 + 9];
#pragma unroll
        for (int k = 0; k < NCPT; ++k) {
            int c = tid + k * BT;
            if (c < n) {
                bool dg = (c == r);
                float t0 = acc[k][0] + (dg ? dred[GW*10+0] : 0.f);
                float t1 = acc[k][1] + (dg ? dred[GW*10+1] : 0.f);
                float t2 = acc[k][2] + (dg ? dred[GW*10+2] : 0.f);
                float t3 = acc[k][3] + (dg ? dred[GW*10+3] : 0.f);
                float t4 = acc[k][4] + (dg ? dred[GW*10+4] : 0.f);
                float t5 = acc[k][5] + (dg ? dred[GW*10+5] : 0.f);
                float t6 = acc[k][6] + (dg ? dred[GW*10+6] : 0.f);
                float t7 = acc[k][7] + (dg ? dred[GW*10+7] : 0.f);
                float t8 = acc[k][8] + (dg ? dred[GW*10+8] : 0.f);
                size_t ro0 = (size_t)(3*r + 0) * n3 + 3*c;
                size_t ro1 = (size_t)(3*r + 1) * n3 + 3*c;
                size_t ro2 = (size_t)(3*r + 2) * n3 + 3*c;
                Ks[ro0+0]=t0; Ks[ro0+1]=t1; Ks[ro0+2]=t2;
                Ks[ro1+0]=t3; Ks[ro1+1]=t4; Ks[ro1+2]=t5;
                Ks[ro2+0]=t6; Ks[ro2+1]=t7; Ks[ro2+2]=t8;
                Ms[ro0+0] = dg ? msdiag : 0.f; Ms[ro0+1] = 0.f; Ms[ro0+2] = 0.f;
                Ms[ro1+0] = 0.f; Ms[ro1+1] = dg ? msdiag : 0.f; Ms[ro1+2] = 0.f;
                Ms[ro2+0] = 0.f; Ms[ro2+1] = 0.f; Ms[ro2+2] = dg ? msdiag : 0.f;
            }
        }
    } else {
        // ========================= fluid =========================
        float accK[NCPT], accM[NCPT];
#pragma unroll
        for (int k = 0; k < NCPT; ++k) { accK[k] = 0.f; accM[k] = 0.f; }
        float dK = 0.f, dM = 0.f;

        for (int vb = 0; vb < T; vb += TCAP) {
            const int Tb = min(T - vb, TCAP);
            for (int c = tid; c < n; c += BT) pcnt[c] = 0;
            __syncthreads();

            for (int v = tid; v < Tb; v += BT) {
                int pk = fetch_entry_bs(ent, Sb, Qb, chunk4, vb + v);
                int e_ = pk >> 2, a = pk & 3;
                int4 nd = elems4[e_];
                float g1x,g1y,g1z,g2x,g2y,g2z,g3x,g3y,g3z,vol;
                tet_geom_f(nodes, nd.x, nd.y, nd.z, nd.w,
                           g1x,g1y,g1z, g2x,g2y,g2z, g3x,g3y,g3z, vol);
                float g0x = -(g1x+g2x+g3x), g0y = -(g1y+g2y+g3y), g0z = -(g1z+g2z+g3z);
                float* V = vis + v * VSTRIDE;
                V[0]=g1x; V[1]=g1y; V[2]=g1z; V[3]=g2x; V[4]=g2y; V[5]=g2z;
                V[6]=g3x; V[7]=g3y; V[8]=g3z; V[9]=vol;
                ((int*)V)[10] = nd.x | (nd.y << 11) | (a << 22);
                ((int*)V)[11] = nd.z | (nd.w << 11);
                float ga0 = sel4(g0x,g1x,g2x,g3x,a);
                float ga1 = sel4(g0y,g1y,g2y,g3y,a);
                float ga2 = sel4(g0z,g1z,g2z,g3z,a);
                dK += vol*(ga0*ga0 + ga1*ga1 + ga2*ga2);
                dM += vol*0.3f;
#pragma unroll
                for (int s = 0; s < 3; ++s) {
                    int b = s + ((s >= a) ? 1 : 0);
                    int cb = sel4i(nd.x, nd.y, nd.z, nd.w, b);
                    atomicAdd(&pcnt[cb], 1);
                }
            }
            __syncthreads();

            {
                const int cs = (n + BT - 1) / BT;
                int cb0 = tid * cs;
                int s = 0;
                for (int k = 0; k < cs; ++k) {
                    int i = cb0 + k;
                    if (i < n) s += pcnt[i];
                }
                int x = s;
#pragma unroll
                for (int d = 1; d < 64; d <<= 1) {
                    int y = __shfl_up(x, d, 64);
                    if ((tid & 63) >= d) x += y;
                }
                if ((tid & 63) == 63) wsp[tid >> 6] = x;
                __syncthreads();
                if (tid == 0) {
                    int run = 0;
                    for (int w = 0; w < GW; ++w) { int t_ = wsp[w]; wsp[w] = run; run += t_; }
                }
                __syncthreads();
                int ex = (x - s) + wsp[tid >> 6];
                for (int k = 0; k < cs; ++k) {
                    int i = cb0 + k;
                    if (i < n) { int c0 = pcnt[i]; pcnt[i] = ex; ex += c0; }
                }
            }
            __syncthreads();

            for (int v = tid; v < Tb; v += BT) {
                const float* V = vis + v * VSTRIDE;
                int w0 = ((const int*)V)[10], w1 = ((const int*)V)[11];
                int a = (w0 >> 22) & 3;
                int c0 = w0 & 2047, c1 = (w0 >> 11) & 2047;
                int c2 = w1 & 2047, c3 = (w1 >> 11) & 2047;
#pragma unroll
                for (int s = 0; s < 3; ++s) {
                    int b = s + ((s >= a) ? 1 : 0);
                    int cb = sel4i(c0, c1, c2, c3, b);
                    int p = atomicAdd(&pcnt[cb], 1);
                    plist[p] = (v << 4) | (a << 2) | b;
                }
            }
            __syncthreads();

#pragma unroll
            for (int k = 0; k < NCPT; ++k) {
                int c = tid + k * BT;
                if (c < n) {
                    int s0 = (c == 0) ? 0 : pcnt[c - 1];
                    int s1 = pcnt[c];
                    for (int p = s0; p < s1; ++p) {
                        int pe = plist[p];
                        int v = pe >> 4, a = (pe >> 2) & 3, b = pe & 3;
                        const float* V = vis + v * VSTRIDE;
                        float g1x=V[0],g1y=V[1],g1z=V[2],g2x=V[3],g2y=V[4],g2z=V[5],
                              g3x=V[6],g3y=V[7],g3z=V[8],vol=V[9];
                        float g0x=-(g1x+g2x+g3x), g0y=-(g1y+g2y+g3y), g0z=-(g1z+g2z+g3z);
                        float ga0=sel4(g0x,g1x,g2x,g3x,a);
                        float ga1=sel4(g0y,g1y,g2y,g3y,a);
                        float ga2=sel4(g0z,g1z,g2z,g3z,a);
                        float gb0=sel4(g0x,g1x,g2x,g3x,b);
                        float gb1=sel4(g0y,g1y,g2y,g3y,b);
                        float gb2=sel4(g0z,g1z,g2z,g3z,b);
                        accK[k] += vol*(ga0*gb0 + ga1*gb1 + ga2*gb2);
                        accM[k] += vol*0.1f;
                    }
                }
            }
            __syncthreads();
        }

        dK = wave_reduce(dK);
        dM = wave_reduce(dM);
        if ((tid & 63) == 0) { int w = tid >> 6; dred[w*2+0] = dK; dred[w*2+1] = dM; }
        __syncthreads();
        if (tid < 2) {
            float t_ = 0.f;
            for (int w = 0; w < GW; ++w) t_ += dred[w*2 + tid];
            dred[GW*2 + tid] = t_;
        }
        __syncthreads();

#pragma unroll
        for (int k = 0; k < NCPT; ++k) {
            int c = tid + k * BT;
            if (c < n) {
                bool dg = (c == r);
                Kf[(size_t)r * n + c] = accK[k] + (dg ? dred[GW*2+0] : 0.f);
                Mf[(size_t)r * n + c] = accM[k] + (dg ? dred[GW*2+1] : 0.f);
            }
        }
    }
}

// --------------------------- fallback scatter path ---------------------------
__device__ __forceinline__ void tet_grads_d(const float* __restrict__ nodes,
                                            const int* ni, double g[4][3], double& vol)
{
    double p[4][3];
#pragma unroll
    for (int a = 0; a < 4; ++a) {
        const float* q = nodes + 3ll * ni[a];
        p[a][0] = (double)q[0]; p[a][1] = (double)q[1]; p[a][2] = (double)q[2];
    }
    double r1[3], r2[3], r3[3];
#pragma unroll
    for (int k = 0; k < 3; ++k) {
        r1[k] = p[1][k] - p[0][k];
        r2[k] = p[2][k] - p[0][k];
        r3[k] = p[3][k] - p[0][k];
    }
    double c23[3] = { r2[1]*r3[2]-r2[2]*r3[1], r2[2]*r3[0]-r2[0]*r3[2], r2[0]*r3[1]-r2[1]*r3[0] };
    double det = r1[0]*c23[0] + r1[1]*c23[1] + r1[2]*c23[2];
    double inv = 1.0 / det;
    double c31[3] = { r3[1]*r1[2]-r3[2]*r1[1], r3[2]*r1[0]-r3[0]*r1[2], r3[0]*r1[1]-r3[1]*r1[0] };
    double c12[3] = { r1[1]*r2[2]-r1[2]*r2[1], r1[2]*r2[0]-r1[0]*r2[2], r1[0]*r2[1]-r1[1]*r2[0] };
#pragma unroll
    for (int k = 0; k < 3; ++k) {
        g[1][k] = c23[k]*inv; g[2][k] = c31[k]*inv; g[3][k] = c12[k]*inv;
        g[0][k] = -(g[1][k] + g[2][k] + g[3][k]);
    }
    vol = fabs(det) / 6.0;
}

__global__ void __launch_bounds__(256)
fluid_assemble(const float* __restrict__ nodes, const int* __restrict__ elems,
               float* __restrict__ Kf, float* __restrict__ Mf, int nelem, int n)
{
    int e = blockIdx.x * blockDim.x + threadIdx.x;
    if (e >= nelem) return;
    const int4 nd = *reinterpret_cast<const int4*>(elems + 4ll * e);
    int ni[4] = { nd.x, nd.y, nd.z, nd.w };
    double g[4][3], vol;
    tet_grads_d(nodes, ni, g, vol);
#pragma unroll
    for (int a = 0; a < 4; ++a) {
        long long rowoff = (long long)ni[a] * n;
#pragma unroll
        for (int b = 0; b < 4; ++b) {
            double kv = vol * (g[a][0]*g[b][0] + g[a][1]*g[b][1] + g[a][2]*g[b][2]);
            double mv = vol * (a == b ? 0.3 : 0.1);
            atomicAdd(Kf + rowoff + ni[b], (float)kv);
            atomicAdd(Mf + rowoff + ni[b], (float)mv);
        }
    }
}

__global__ void __launch_bounds__(256)
solid_assemble(const float* __restrict__ nodes, const int* __restrict__ elems,
               float* __restrict__ Ks, float* __restrict__ Ms,
               const float* __restrict__ E_p, const float* __restrict__ nu_p,
               const float* __restrict__ rho_p, int nelem, int n3)
{
    int e = blockIdx.x * blockDim.x + threadIdx.x;
    if (e >= nelem) return;
    double E = (double)*E_p, nu = (double)*nu_p, rho = (double)*rho_p;
    double coeff = E / ((1.0 + nu) * (1.0 - 2.0 * nu));
    double lam = coeff * nu, mu = coeff * (1.0 - 2.0 * nu) * 0.5;
    const int4 nd = *reinterpret_cast<const int4*>(elems + 4ll * e);
    int ni[4] = { nd.x, nd.y, nd.z, nd.w };
    double g[4][3], vol;
    tet_grads_d(nodes, ni, g, vol);
    double lv = lam * vol, mv = mu * vol;
#pragma unroll
    for (int a = 0; a < 4; ++a) {
        long long row0 = 3ll * ni[a];
#pragma unroll
        for (int b = 0; b < 4; ++b) {
            long long col0 = 3ll * ni[b];
            double gg = g[a][0]*g[b][0] + g[a][1]*g[b][1] + g[a][2]*g[b][2];
#pragma unroll
            for (int i = 0; i < 3; ++i) {
                float* rowp = Ks + (row0 + i) * (long long)n3 + col0;
#pragma unroll
                for (int j = 0; j < 3; ++j) {
                    double val = lv * g[a][i] * g[b][j] + mv * g[a][j] * g[b][i];
                    if (i == j) val += mv * gg;
                    atomicAdd(rowp + j, (float)val);
                }
            }
        }
        float mval = (float)(rho * vol * 0.25);
#pragma unroll
        for (int i = 0; i < 3; ++i) {
            long long d = row0 + i;
            atomicAdd(Ms + d * (long long)n3 + d, mval);
        }
    }
}

// ---------------------------------------------------------------------------
extern "C" void kernel_launch(void* const* d_in, const int* in_sizes, int n_in,
                              void* d_out, int out_size, void* d_ws, size_t ws_size,
                              hipStream_t stream)
{
    const float* nodes = (const float*)d_in[0];
    const int*   fe    = (const int*)d_in[1];
    const int*   se    = (const int*)d_in[2];
    const float* E_p   = (const float*)d_in[3];
    const float* nu_p  = (const float*)d_in[4];
    const float* rho_p = (const float*)d_in[5];

    const int n  = in_sizes[0] / 3;
    const int nf = in_sizes[1] / 4;
    const int ns = in_sizes[2] / 4;
    const int n3 = 3 * n;

    float* out = (float*)d_out;
    float* Kf = out;
    float* Mf = Kf + (size_t)n * n;
    float* Ks = Mf + (size_t)n * n;
    float* Ms = Ks + (size_t)n3 * n3;

    const int chunkF = (nf + G_PART - 1) / G_PART;
    const int chunkS = (ns + G_PART - 1) / G_PART;

    size_t pos = 0;
    auto take = [&](size_t bytes) {
        size_t p = pos;
        pos = (pos + bytes + 255) & ~(size_t)255;
        return p;
    };
    size_t entF_o = take((size_t)4 * chunkF * G_PART * 4);
    size_t entS_o = take((size_t)4 * chunkS * G_PART * 4);
    size_t PF_o   = take((size_t)(n + 1) * G_PART * 4);
    size_t PS_o   = take((size_t)(n + 1) * G_PART * 4);

    size_t gatherLds = (size_t)TCAP * VSTRIDE * 4 + (size_t)n * 4
                     + (size_t)3 * TCAP * 4 + (256 + 257 + GW) * 4
                     + (GW * 10 + 10) * 4;
    size_t indexLds  = (size_t)(n + 256) * 4;
    bool gather_ok = (pos <= ws_size) && (n <= 2048) && (n <= NCPT * BT) &&
                     (gatherLds <= 80 * 1024) && (indexLds <= 64 * 1024);

    const int bs = 256;

    if (!gather_ok) {
        hipMemsetAsync(d_out, 0, (size_t)out_size * sizeof(float), stream);
        fluid_assemble<<<(nf + bs - 1) / bs, bs, 0, stream>>>(nodes, fe, Kf, Mf, nf, n);
        solid_assemble<<<(ns + bs - 1) / bs, bs, 0, stream>>>(nodes, se, Ks, Ms,
                                                              E_p, nu_p, rho_p, ns, n3);
        return;
    }

    char* ws = (char*)d_ws;
    int* entF = (int*)(ws + entF_o);
    int* entS = (int*)(ws + entS_o);
    int* PF   = (int*)(ws + PF_o);
    int* PS   = (int*)(ws + PS_o);

    const int4* fe4 = (const int4*)fe;
    const int4* se4 = (const int4*)se;

    index_build<<<2 * G_PART, bs, indexLds, stream>>>(fe4, se4, entF, entS, PF, PS,
                                                      nf, ns, n, chunkF, chunkS);
    fused_gather<<<2 * n, BT, gatherLds, stream>>>(entF, PF, entS, PS,
                                                   fe4, se4, nodes,
                                                   Kf, Mf, Ks, Ms,
                                                   E_p, nu_p, rho_p, n, n3,
                                                   4 * chunkF, 4 * chunkS);
}